// Round 1
// baseline (16488.651 us; speedup 1.0000x reference)
//
#include <hip/hip_runtime.h>

typedef __attribute__((ext_vector_type(8))) short s16x8;
typedef __attribute__((ext_vector_type(4))) float f32x4;

#define B_ 64
#define T_ 512
#define H_ 1024
#define G4 4096      // 4*H
#define K2 2048      // D + H (fused input+recurrent K)

__device__ __forceinline__ short f2bf(float f) {
  union { float f; unsigned u; } x; x.f = f;
  unsigned r = (x.u + 0x7fffu + ((x.u >> 16) & 1u)) >> 16;  // RNE
  return (short)r;
}

// One grid-stride prep kernel: pack weights to bf16 [L][4096][2048] (cols: 0..1023=W_ih,
// 1024..2047=W_hh, rows contiguous in K = MFMA B-frag layout), fold biases, convert x to
// bf16, init h (bf16, parity-1 buffers) and c (fp32) from hx/cx. ws is poisoned 0xAA
// before every timed call, so everything read later must be rewritten here.
__global__ void prep_kernel(const float* __restrict__ input_, const float* __restrict__ hx,
                            const float* __restrict__ cx, const float* __restrict__ W_ih,
                            const float* __restrict__ W_hh, const float* __restrict__ b_ih,
                            const float* __restrict__ b_hh,
                            short* __restrict__ Wcat, float* __restrict__ bias,
                            short* __restrict__ Xbf, short* __restrict__ h0buf,
                            short* __restrict__ h1buf, float* __restrict__ c0,
                            float* __restrict__ c1, int use_xbf)
{
  const long total = 33554432;  // B*T*H
  for (long idx = (long)blockIdx.x * blockDim.x + threadIdx.x; idx < total;
       idx += (long)gridDim.x * blockDim.x) {
    if (use_xbf) Xbf[idx] = f2bf(input_[idx]);
    if (idx < 16777216) {                      // 2 * 4096 * 2048
      long l = idx >> 23;                      // / (4096*2048)
      long r = idx & 8388607;
      long j = r >> 11, k = r & 2047;
      float v = (k < 1024) ? W_ih[((l << 12) + j) * 1024 + k]
                           : W_hh[((l << 12) + j) * 1024 + (k - 1024)];
      Wcat[idx] = f2bf(v);
    }
    if (idx < 8192) bias[idx] = b_ih[idx] + b_hh[idx];
    if (idx < 65536) {                         // B*H
      long b = idx >> 10, n = idx & 1023;
      h0buf[65536 + idx] = f2bf(hx[(b * 2 + 0) * 1024 + n]);  // parity-1 read at s=0/1
      h1buf[65536 + idx] = f2bf(hx[(b * 2 + 1) * 1024 + n]);
      c0[idx] = cx[(b * 2 + 0) * 1024 + n];
      c1[idx] = cx[(b * 2 + 1) * 1024 + n];
    }
  }
}

// Launch s in [0,512]: blocks 0..127 run layer0 step t=s (if s<512), blocks 128..255 run
// layer1 step t=s-1 (if s>=1). h double-buffered by parity; c slices are block-exclusive.
// Block: 256 threads = 4 waves (wave = M-tile of 16 batches), computes [64 x 32] gate tile
// (8 n-columns x {i,f,g,o}) with K=2048 via mfma_f32_16x16x32_bf16, then block-local
// pointwise through LDS.
template <int XBF>
__global__ __launch_bounds__(256)
void lstm_step(const short* __restrict__ Wcat, const float* __restrict__ bias,
               const short* __restrict__ Xbf, const float* __restrict__ xf32,
               short* __restrict__ h0buf, short* __restrict__ h1buf,
               float* __restrict__ c0, float* __restrict__ c1,
               float* __restrict__ out, int s)
{
  const int blk = blockIdx.x;
  const int layer = blk >> 7;
  const int nblk = blk & 127;
  if (layer == 0 && s == T_) return;
  if (layer == 1 && s == 0) return;
  const int t = (layer == 0) ? s : (s - 1);

  const short* W = Wcat + (long)layer * (G4 * K2);
  const int lane = threadIdx.x & 63;
  const int wave = threadIdx.x >> 6;
  const int quad = lane >> 4;
  const int lo = lane & 15;
  const int n0 = nblk * 8;
  const int b = wave * 16 + lo;   // A-row = batch

  // A-operand sources: k<1024 -> x part, k>=1024 -> h_prev part
  const short* xrow_bf = nullptr;
  const float* xrow_f = nullptr;
  const short* hrow;
  if (layer == 0) {
    if (XBF) xrow_bf = Xbf + ((long)(b * T_ + t)) * H_;
    else     xrow_f  = xf32 + ((long)(b * T_ + t)) * H_;
    hrow = h0buf + ((s + 1) & 1) * 65536 + b * H_;
  } else {
    xrow_bf = h0buf + ((s + 1) & 1) * 65536 + b * H_;   // h0_t from previous launch
    hrow    = h1buf + (s & 1) * 65536 + b * H_;
  }

  // B-operand rows: tile col n -> gate row j = (n/8)*1024 + n0 + n%8  (i,f,g,o grouping)
  const short* wrow0; const short* wrow1;
  { int n = lo;      int j = (n >> 3) * H_ + n0 + (n & 7); wrow0 = W + (long)j * K2; }
  { int n = 16 + lo; int j = (n >> 3) * H_ + n0 + (n & 7); wrow1 = W + (long)j * K2; }

  f32x4 acc0 = {0.f, 0.f, 0.f, 0.f}, acc1 = {0.f, 0.f, 0.f, 0.f};

#pragma unroll 4
  for (int k0 = 0; k0 < K2; k0 += 32) {
    const int koff = k0 + quad * 8;   // wave-uniform branch: k0+24 < 1024 iff k0 < 1024
    s16x8 af;
    if (koff < H_) {
      if (XBF || layer == 1) {
        af = *(const s16x8*)(xrow_bf + koff);
      } else {
        const float* p = xrow_f + koff;
        s16x8 tmp;
#pragma unroll
        for (int e = 0; e < 8; e++) tmp[e] = f2bf(p[e]);
        af = tmp;
      }
    } else {
      af = *(const s16x8*)(hrow + (koff - H_));
    }
    const s16x8 bf0 = *(const s16x8*)(wrow0 + koff);
    const s16x8 bf1 = *(const s16x8*)(wrow1 + koff);
    acc0 = __builtin_amdgcn_mfma_f32_16x16x32_bf16(af, bf0, acc0, 0, 0, 0);
    acc1 = __builtin_amdgcn_mfma_f32_16x16x32_bf16(af, bf1, acc1, 0, 0, 0);
  }

  // C/D layout: row(m) = quad*4 + reg, col(n) = lo  [verified m89/m91]
  __shared__ float gbuf[64][33];
#pragma unroll
  for (int r = 0; r < 4; r++) {
    int m = wave * 16 + quad * 4 + r;
    gbuf[m][lo] = acc0[r];
    gbuf[m][16 + lo] = acc1[r];
  }
  __syncthreads();

  float* cbuf = layer ? c1 : c0;
  short* hdst = layer ? (h1buf + ((s + 1) & 1) * 65536) : (h0buf + (s & 1) * 65536);
  const float* bl = bias + layer * G4;

  for (int p = threadIdx.x; p < 512; p += 256) {
    int bb = p >> 3, nl = p & 7;
    int nn = n0 + nl;
    float ig = gbuf[bb][nl]      + bl[nn];
    float fg = gbuf[bb][8 + nl]  + bl[1024 + nn];
    float gg = gbuf[bb][16 + nl] + bl[2048 + nn];
    float og = gbuf[bb][24 + nl] + bl[3072 + nn];
    int ci = bb * H_ + nn;
    float cp = cbuf[ci];
    float si = 1.f / (1.f + __expf(-ig));
    float sf = 1.f / (1.f + __expf(-fg));
    float so = 1.f / (1.f + __expf(-og));
    float cn = sf * cp + si * tanhf(gg);
    float hn = so * tanhf(cn);
    cbuf[ci] = cn;
    hdst[ci] = f2bf(hn);
    if (layer) {
      out[((long)bb * T_ + t) * H_ + nn] = hn;   // new_output [B,T,H]
      if (t == T_ - 1) {
        out[33554432L + ci] = hn;                 // hT[-1] [B,H]
        out[33554432L + 65536 + ci] = cn;         // cT[-1] [B,H]
      }
    }
  }
}

extern "C" void kernel_launch(void* const* d_in, const int* in_sizes, int n_in,
                              void* d_out, int out_size, void* d_ws, size_t ws_size,
                              hipStream_t stream)
{
  const float* input_ = (const float*)d_in[0];
  const float* hx   = (const float*)d_in[1];
  const float* cx   = (const float*)d_in[2];
  const float* W_ih = (const float*)d_in[3];
  const float* W_hh = (const float*)d_in[4];
  const float* b_ih = (const float*)d_in[5];
  const float* b_hh = (const float*)d_in[6];
  float* out = (float*)d_out;

  char* w = (char*)d_ws;
  size_t off = 0;
  short* Wcat = (short*)(w + off); off += 33554432;        // 2*4096*2048 bf16
  float* bias = (float*)(w + off); off += 32768;           // 2*4096 fp32
  // optional bf16 copy of input (67 MB) — fall back to fp32 reads if ws is small
  size_t state_bytes = 4 * 262144;                          // h0,h1 (bf16 x2 parity), c0,c1
  int use_xbf = (ws_size >= off + 67108864 + state_bytes) ? 1 : 0;
  short* Xbf = nullptr;
  if (use_xbf) { Xbf = (short*)(w + off); off += 67108864; }
  short* h0buf = (short*)(w + off); off += 262144;
  short* h1buf = (short*)(w + off); off += 262144;
  float* c0 = (float*)(w + off); off += 262144;
  float* c1 = (float*)(w + off); off += 262144;

  hipLaunchKernelGGL(prep_kernel, dim3(4096), dim3(256), 0, stream,
                     input_, hx, cx, W_ih, W_hh, b_ih, b_hh,
                     Wcat, bias, Xbf, h0buf, h1buf, c0, c1, use_xbf);

  if (use_xbf) {
    for (int s = 0; s <= T_; s++)
      hipLaunchKernelGGL((lstm_step<1>), dim3(256), dim3(256), 0, stream,
                         Wcat, bias, Xbf, input_, h0buf, h1buf, c0, c1, out, s);
  } else {
    for (int s = 0; s <= T_; s++)
      hipLaunchKernelGGL((lstm_step<0>), dim3(256), dim3(256), 0, stream,
                         Wcat, bias, Xbf, input_, h0buf, h1buf, c0, c1, out, s);
  }
}

// Round 2
// 10129.812 us; speedup vs baseline: 1.6277x; 1.6277x over previous
//
#include <hip/hip_runtime.h>

typedef __attribute__((ext_vector_type(8))) short s16x8;
typedef __attribute__((ext_vector_type(4))) float f32x4;

#define B_ 64
#define T_ 512
#define H_ 1024
#define G4 4096      // 4*H
#define K2 2048      // D + H (fused input+recurrent K)

__device__ __forceinline__ short f2bf(float f) {
  union { float f; unsigned u; } x; x.f = f;
  unsigned r = (x.u + 0x7fffu + ((x.u >> 16) & 1u)) >> 16;  // RNE
  return (short)r;
}

__device__ __forceinline__ float fast_sigmoid(float x) {
  return 1.f / (1.f + __expf(-x));
}
__device__ __forceinline__ float fast_tanh(float x) {
  float e = __expf(-2.f * fabsf(x));          // overflow-safe
  float t = (1.f - e) / (1.f + e);
  return copysignf(t, x);
}

// Prep (one grid-stride kernel, ws re-poisoned 0xAA each call so rebuild everything):
//  Wp   [L][128 nblk][64 iter][2 frag][64 lane][8]  bf16  — exact wave-read order (coalesced B)
//  Xp   [T][128 chunk][64 b][8]                     bf16  — A-fragment chunked layout for x
//  h0/h1 [2 parity][128 chunk][64 b][8]             bf16  — same chunked layout (epilogue writes it)
//  c0/c1 [128 nblk][64 b][8]                        fp32  — block-private contiguous
__global__ void prep_kernel(const float* __restrict__ input_, const float* __restrict__ hx,
                            const float* __restrict__ cx, const float* __restrict__ W_ih,
                            const float* __restrict__ W_hh, const float* __restrict__ b_ih,
                            const float* __restrict__ b_hh,
                            short* __restrict__ Wp, float* __restrict__ bias,
                            short* __restrict__ Xp, short* __restrict__ h0buf,
                            short* __restrict__ h1buf, float* __restrict__ c0,
                            float* __restrict__ c1, int use_xbf)
{
  const long total = use_xbf ? 33554432L : 16777216L;
  for (long idx = (long)blockIdx.x * blockDim.x + threadIdx.x; idx < total;
       idx += (long)gridDim.x * blockDim.x) {
    if (use_xbf && idx < 33554432L) {
      // Xp[((t*128 + c)*64 + b)*8 + e] = x[b][t][c*8+e]
      int e = idx & 7;
      int b = (idx >> 3) & 63;
      long tc = idx >> 9;
      int c = (int)(tc & 127);
      int t = (int)(tc >> 7);
      Xp[idx] = f2bf(input_[((long)b * T_ + t) * H_ + c * 8 + e]);
    }
    if (idx < 16777216L) {
      // Wp flat: [(layer*128+nblk)][r], r = ((iter*2+frag)*64+lane)*8+e
      int lb = (int)(idx >> 16);            // layer*128+nblk
      int layer = lb >> 7, nblk = lb & 127;
      int r = (int)(idx & 65535);
      int e = r & 7;
      int lane = (r >> 3) & 63;
      int fragiter = r >> 9;
      int frag = fragiter & 1, iter = fragiter >> 1;
      int n = frag * 16 + (lane & 15);
      int k = iter * 32 + (lane >> 4) * 8 + e;
      int j = (n >> 3) * H_ + nblk * 8 + (n & 7);   // gate row (i,f,g,o grouped per block)
      float v = (k < H_) ? W_ih[((long)(layer << 12) + j) * H_ + k]
                         : W_hh[((long)(layer << 12) + j) * H_ + (k - H_)];
      Wp[idx] = f2bf(v);
    }
    if (idx < 8192) bias[idx] = b_ih[idx] + b_hh[idx];
    if (idx < 65536) {
      int b = (int)(idx >> 10), n = (int)(idx & 1023);
      int pi = (n >> 3) * 512 + b * 8 + (n & 7);    // chunked layout
      h0buf[65536 + pi] = f2bf(hx[(b * 2 + 0) * H_ + n]);  // parity-1 initial state
      h1buf[65536 + pi] = f2bf(hx[(b * 2 + 1) * H_ + n]);
      c0[pi] = cx[(b * 2 + 0) * H_ + n];
      c1[pi] = cx[(b * 2 + 1) * H_ + n];
    }
  }
}

// Launch s in [0,512]: blocks 0..127 = layer0@t=s, blocks 128..255 = layer1@t=s-1.
// All k-loop loads are coalesced: B from Wp in wave-read order, A from chunked x/h.
template <int XBF>
__global__ __launch_bounds__(256)
void lstm_step(const short* __restrict__ Wp, const float* __restrict__ bias,
               const short* __restrict__ Xp, const float* __restrict__ xf32,
               short* __restrict__ h0buf, short* __restrict__ h1buf,
               float* __restrict__ c0, float* __restrict__ c1,
               float* __restrict__ out, int s)
{
  const int blk = blockIdx.x;
  const int layer = blk >> 7;
  const int nblk = blk & 127;
  if (layer == 0 && s == T_) return;
  if (layer == 1 && s == 0) return;
  const int t = (layer == 0) ? s : (s - 1);

  const int lane = threadIdx.x & 63;
  const int wave = threadIdx.x >> 6;
  const int quad = lane >> 4;
  const int lo = lane & 15;
  const int n0 = nblk * 8;
  const int b = wave * 16 + lo;   // A-row = batch

  // A bases (chunked layout: addr = base + koff*64 + b*8), B base (wave-read order)
  const short* baseX;             // k in [0,1024)
  const short* baseH;             // k in [1024,2048)
  const float* xrow_f = nullptr;  // XBF=0 fallback: per-lane fp32 gather
  if (layer == 0) {
    baseX = Xp + (long)t * 65536;
    if (!XBF) xrow_f = xf32 + ((long)b * T_ + t) * H_;
    baseH = h0buf + ((s + 1) & 1) * 65536;
  } else {
    baseX = h0buf + ((s + 1) & 1) * 65536;   // h0_t from previous launch
    baseH = h1buf + (s & 1) * 65536;
  }
  const short* pAx = baseX + b * 8;
  const short* pAh = baseH + b * 8;
  const short* wbase = Wp + ((long)(layer * 128 + nblk) << 16) + lane * 8;

  f32x4 acc0 = {0.f, 0.f, 0.f, 0.f}, acc1 = {0.f, 0.f, 0.f, 0.f};

#pragma unroll 4
  for (int k0 = 0; k0 < K2; k0 += 32) {
    const int koff = k0 + quad * 8;   // branch is uniform per k0 (k0+24 < 1024 iff k0 < 1024)
    s16x8 af;
    if (koff < H_) {
      if (XBF || layer == 1) {
        af = *(const s16x8*)(pAx + koff * 64);
      } else {
        const float* p = xrow_f + koff;
        s16x8 tmp;
#pragma unroll
        for (int e = 0; e < 8; e++) tmp[e] = f2bf(p[e]);
        af = tmp;
      }
    } else {
      af = *(const s16x8*)(pAh + (koff - H_) * 64);
    }
    const s16x8 bf0 = *(const s16x8*)(wbase + k0 * 32);        // iter*1024
    const s16x8 bf1 = *(const s16x8*)(wbase + k0 * 32 + 512);  // frag 1
    acc0 = __builtin_amdgcn_mfma_f32_16x16x32_bf16(af, bf0, acc0, 0, 0, 0);
    acc1 = __builtin_amdgcn_mfma_f32_16x16x32_bf16(af, bf1, acc1, 0, 0, 0);
  }

  // C/D layout: row(m) = quad*4 + reg, col(n) = lo  [verified m89/m91]
  __shared__ float gbuf[64][33];
#pragma unroll
  for (int r = 0; r < 4; r++) {
    int m = wave * 16 + quad * 4 + r;
    gbuf[m][lo] = acc0[r];
    gbuf[m][16 + lo] = acc1[r];
  }
  __syncthreads();

  float* cb = (layer ? c1 : c0) + nblk * 512;
  short* hdst = (layer ? h1buf : h0buf) + ((layer ? (s + 1) : s) & 1) * 65536 + nblk * 512;
  const float* bl = bias + layer * G4;

  for (int p = threadIdx.x; p < 512; p += 256) {
    int bb = p >> 3, nl = p & 7;
    int nn = n0 + nl;
    float ig = gbuf[bb][nl]      + bl[nn];
    float fg = gbuf[bb][8 + nl]  + bl[1024 + nn];
    float gg = gbuf[bb][16 + nl] + bl[2048 + nn];
    float og = gbuf[bb][24 + nl] + bl[3072 + nn];
    float cp = cb[p];
    float si = fast_sigmoid(ig);
    float sf = fast_sigmoid(fg);
    float so = fast_sigmoid(og);
    float cn = sf * cp + si * fast_tanh(gg);
    float hn = so * fast_tanh(cn);
    cb[p] = cn;
    hdst[p] = f2bf(hn);
    if (layer) {
      out[((long)bb * T_ + t) * H_ + nn] = hn;    // new_output [B,T,H]
      if (t == T_ - 1) {
        out[33554432L + bb * H_ + nn] = hn;       // hT[-1]
        out[33554432L + 65536 + bb * H_ + nn] = cn; // cT[-1]
      }
    }
  }
}

extern "C" void kernel_launch(void* const* d_in, const int* in_sizes, int n_in,
                              void* d_out, int out_size, void* d_ws, size_t ws_size,
                              hipStream_t stream)
{
  const float* input_ = (const float*)d_in[0];
  const float* hx   = (const float*)d_in[1];
  const float* cx   = (const float*)d_in[2];
  const float* W_ih = (const float*)d_in[3];
  const float* W_hh = (const float*)d_in[4];
  const float* b_ih = (const float*)d_in[5];
  const float* b_hh = (const float*)d_in[6];
  float* out = (float*)d_out;

  char* w = (char*)d_ws;
  size_t off = 0;
  short* Wp  = (short*)(w + off); off += 33554432;        // 2*128*64*2*64*8 bf16
  float* bias = (float*)(w + off); off += 32768;          // 2*4096 fp32
  size_t state_bytes = 4 * 262144;                        // h0,h1 (bf16 x2 parity), c0,c1
  int use_xbf = (ws_size >= off + 67108864 + state_bytes) ? 1 : 0;
  short* Xp = nullptr;
  if (use_xbf) { Xp = (short*)(w + off); off += 67108864; }
  short* h0buf = (short*)(w + off); off += 262144;
  short* h1buf = (short*)(w + off); off += 262144;
  float* c0 = (float*)(w + off); off += 262144;
  float* c1 = (float*)(w + off); off += 262144;

  hipLaunchKernelGGL(prep_kernel, dim3(4096), dim3(256), 0, stream,
                     input_, hx, cx, W_ih, W_hh, b_ih, b_hh,
                     Wp, bias, Xp, h0buf, h1buf, c0, c1, use_xbf);

  if (use_xbf) {
    for (int s = 0; s <= T_; s++)
      hipLaunchKernelGGL((lstm_step<1>), dim3(256), dim3(256), 0, stream,
                         Wp, bias, Xp, input_, h0buf, h1buf, c0, c1, out, s);
  } else {
    for (int s = 0; s <= T_; s++)
      hipLaunchKernelGGL((lstm_step<0>), dim3(256), dim3(256), 0, stream,
                         Wp, bias, Xp, input_, h0buf, h1buf, c0, c1, out, s);
  }
}